// Round 1
// baseline (249.529 us; speedup 1.0000x reference)
//
#include <hip/hip_runtime.h>
#include <math.h>

#define NP 261121   // 511*511

// ---------------- K0: weight transposes for scalar-load-friendly layouts ----
__global__ __launch_bounds__(256) void k_prep(const float* __restrict__ w_c9a,
                                              const float* __restrict__ w_c9b,
                                              float* __restrict__ wTa,
                                              float* __restrict__ wTb)
{
    int t = blockIdx.x * 256 + threadIdx.x;
    if (t < 288) {                       // wTa[k*32+o] = w_c9a[o*9+k]
        int o = t & 31, k = t >> 5;
        wTa[t] = w_c9a[o * 9 + k];
    }
    if (t < 18432) {                     // wTb[(c*9+k)*64+o] = w_c9b[o*288 + c*9+k]
        int o = t & 63, ck = t >> 6;
        wTb[t] = w_c9b[o * 288 + ck];
    }
}

// ---------------- K1: fused 1x1 convs 204->16->8->1 (relu each) -------------
__global__ __launch_bounds__(256) void k_conv123(const float* __restrict__ x,
                                                 const float* __restrict__ w1,
                                                 const float* __restrict__ b1,
                                                 const float* __restrict__ w2,
                                                 const float* __restrict__ b2,
                                                 const float* __restrict__ w3,
                                                 const float* __restrict__ b3,
                                                 float* __restrict__ tmp12)
{
    __shared__ float s_w1[204 * 16];
    __shared__ float s_misc[192]; // [0..127]=w2, [128..135]=w3, [136..151]=b1, [152..159]=b2, [160]=b3
    int t = threadIdx.x;
    for (int i = t; i < 204 * 16; i += 256)
        s_w1[i] = w1[(i & 15) * 204 + (i >> 4)];  // [c][o]
    if (t < 128) s_misc[t] = w2[t];
    else if (t < 136) s_misc[t] = w3[t - 128];
    else if (t < 152) s_misc[t] = b1[t - 136];
    else if (t < 160) s_misc[t] = b2[t - 152];
    else if (t == 160) s_misc[160] = b3[0];
    __syncthreads();

    int p = blockIdx.x * 256 + t;
    if (p >= NP) return;

    float acc[16];
#pragma unroll
    for (int o = 0; o < 16; ++o) acc[o] = 0.f;

    const float* xp = x + p;
#pragma unroll 4
    for (int c = 0; c < 204; ++c) {
        float xv = xp[(size_t)c * NP];
        const float4* wv = reinterpret_cast<const float4*>(s_w1 + c * 16);
        float wl[16];
        *reinterpret_cast<float4*>(&wl[0])  = wv[0];
        *reinterpret_cast<float4*>(&wl[4])  = wv[1];
        *reinterpret_cast<float4*>(&wl[8])  = wv[2];
        *reinterpret_cast<float4*>(&wl[12]) = wv[3];
#pragma unroll
        for (int o = 0; o < 16; ++o) acc[o] = fmaf(xv, wl[o], acc[o]);
    }

    float f1[16];
#pragma unroll
    for (int o = 0; o < 16; ++o) f1[o] = fmaxf(acc[o] + s_misc[136 + o], 0.f);

    float tmp = s_misc[160];
#pragma unroll
    for (int j = 0; j < 8; ++j) {
        float s = s_misc[152 + j];
#pragma unroll
        for (int o = 0; o < 16; ++o) s = fmaf(f1[o], s_misc[j * 16 + o], s);
        tmp = fmaf(fmaxf(s, 0.f), s_misc[128 + j], tmp);
    }
    tmp12[p] = fmaxf(tmp, 0.f);
}

// ------------- K2: Haar DWT (zero-pad) + 1x1 conv(pad=1) + pixel_shuffle ----
__global__ __launch_bounds__(256) void k_dwt_hi(const float* __restrict__ tmp12,
                                                const float* __restrict__ w_hi,
                                                const float* __restrict__ b_hi,
                                                float* __restrict__ hf)
{
    const float INV = 0.70710678118654752440f; // f32(1/sqrt(2))
    int idx = blockIdx.x * 256 + threadIdx.x;
    if (idx >= 258 * 258) return;
    int h = idx / 258, w = idx - h * 258;

    float wh[12], bh[4];
#pragma unroll
    for (int i = 0; i < 12; ++i) wh[i] = w_hi[i];
#pragma unroll
    for (int o = 0; o < 4; ++o) bh[o] = b_hi[o];

    float v[4];
    if (h == 0 || h == 257 || w == 0 || w == 257) {
#pragma unroll
        for (int o = 0; o < 4; ++o) v[o] = fmaxf(bh[o], 0.f);
    } else {
        int hh = h - 1, ww = w - 1;
        int r0 = 2 * hh, r1 = 2 * hh + 1, c0 = 2 * ww, c1 = 2 * ww + 1;
        float a = tmp12[r0 * 511 + c0];
        float b = (c1 < 511) ? tmp12[r0 * 511 + c1] : 0.f;
        float c = (r1 < 511) ? tmp12[r1 * 511 + c0] : 0.f;
        float d = (r1 < 511 && c1 < 511) ? tmp12[r1 * 511 + c1] : 0.f;
        float lo0 = (a + b) * INV, hi0 = (a - b) * INV;
        float lo1 = (c + d) * INV, hi1 = (c - d) * INV;
        float cH = (lo0 - lo1) * INV;
        float cV = (hi0 + hi1) * INV;
        float cD = (hi0 - hi1) * INV;
#pragma unroll
        for (int o = 0; o < 4; ++o)
            v[o] = fmaxf(wh[o * 3 + 0] * cH + wh[o * 3 + 1] * cV + wh[o * 3 + 2] * cD + bh[o], 0.f);
    }
    int orow = (2 * h) * 516 + 2 * w;
    hf[orow]       = v[0];
    hf[orow + 1]   = v[1];
    hf[orow + 516] = v[2];
    hf[orow + 517] = v[3];
}

// ---------------- K3: 5x5 separable gaussian blur, reflect pad --------------
__global__ __launch_bounds__(256) void k_blur(const float* __restrict__ hf,
                                              float* __restrict__ hfb,
                                              float g0, float g1, float g2)
{
    int idx = blockIdx.x * 256 + threadIdx.x;
    if (idx >= 516 * 516) return;
    int y = idx / 516, x = idx - y * 516;
    float g[5] = {g0, g1, g2, g1, g0};
    int ry[5], rx[5];
#pragma unroll
    for (int i = 0; i < 5; ++i) {
        int yy = y + i - 2; yy = yy < 0 ? -yy : (yy > 515 ? 1030 - yy : yy);
        int xx = x + i - 2; xx = xx < 0 ? -xx : (xx > 515 ? 1030 - xx : xx);
        ry[i] = yy * 516; rx[i] = xx;
    }
    float s = 0.f;
#pragma unroll
    for (int i = 0; i < 5; ++i) {
        float rs = 0.f;
#pragma unroll
        for (int j = 0; j < 5; ++j) rs = fmaf(g[j], hf[ry[i] + rx[j]], rs);
        s = fmaf(g[i], rs, s);
    }
    hfb[idx] = s;
}

// ---------------- K4: global mean/max reduction -> sigmoid gate -------------
__global__ __launch_bounds__(256) void k_red1(const float* __restrict__ hfb,
                                              float* __restrict__ psum,
                                              float* __restrict__ pmax)
{
    __shared__ float ss[256], sm[256];
    int t = threadIdx.x;
    int gid = blockIdx.x * 256 + t;
    float s = 0.f, m = -3.4e38f;
    for (int i = gid; i < 516 * 516; i += 65536) { float v = hfb[i]; s += v; m = fmaxf(m, v); }
    ss[t] = s; sm[t] = m;
    __syncthreads();
    for (int off = 128; off > 0; off >>= 1) {
        if (t < off) { ss[t] += ss[t + off]; sm[t] = fmaxf(sm[t], sm[t + off]); }
        __syncthreads();
    }
    if (t == 0) { psum[blockIdx.x] = ss[0]; pmax[blockIdx.x] = sm[0]; }
}

__global__ __launch_bounds__(256) void k_red2(const float* __restrict__ psum,
                                              const float* __restrict__ pmax,
                                              const float* __restrict__ caw1,
                                              const float* __restrict__ caw2,
                                              float* __restrict__ scale)
{
    __shared__ float ss[256], sm[256];
    int t = threadIdx.x;
    ss[t] = psum[t]; sm[t] = pmax[t];
    __syncthreads();
    for (int off = 128; off > 0; off >>= 1) {
        if (t < off) { ss[t] += ss[t + off]; sm[t] = fmaxf(sm[t], sm[t + off]); }
        __syncthreads();
    }
    if (t == 0) {
        float avg = ss[0] / 266256.f;
        float mx = sm[0];
        float a = caw1[0], b = caw2[0];
        float z = b * fmaxf(a * avg, 0.f) + b * fmaxf(a * mx, 0.f);
        scale[0] = 1.f / (1.f + expf(-z));
    }
}

// ---------------- K5: 6x6 valid conv (scale folded) + bias + relu + residual
__global__ __launch_bounds__(256) void k_cat(const float* __restrict__ hfb,
                                             const float* __restrict__ tmp12,
                                             const float* __restrict__ w_cat,
                                             const float* __restrict__ b_cat,
                                             const float* __restrict__ scale,
                                             float* __restrict__ f12)
{
    int p = blockIdx.x * 256 + threadIdx.x;
    if (p >= NP) return;
    int y = p / 511, x = p - y * 511;
    float sc = scale[0];
    float s = 0.f;
#pragma unroll
    for (int ky = 0; ky < 6; ++ky) {
        const float* row = hfb + (y + ky) * 516 + x;
#pragma unroll
        for (int kx = 0; kx < 6; ++kx) s = fmaf(row[kx], w_cat[ky * 6 + kx], s);
    }
    f12[p] = tmp12[p] + fmaxf(sc * s + b_cat[0], 0.f);
}

// ---------------- K6: 3x3 conv 1->32, pad 1, relu ---------------------------
__global__ __launch_bounds__(256) void k_c9a(const float* __restrict__ f12,
                                             const float* __restrict__ wTa,
                                             const float* __restrict__ bias,
                                             float* __restrict__ h)
{
    int p = blockIdx.x * 256 + threadIdx.x;
    if (p >= NP) return;
    int y = p / 511, x = p - y * 511;
    float hv[9];
#pragma unroll
    for (int ky = 0; ky < 3; ++ky)
#pragma unroll
        for (int kx = 0; kx < 3; ++kx) {
            int yy = y + ky - 1, xx = x + kx - 1;
            hv[ky * 3 + kx] = (yy >= 0 && yy < 511 && xx >= 0 && xx < 511) ? f12[yy * 511 + xx] : 0.f;
        }
    float acc[32];
#pragma unroll
    for (int o = 0; o < 32; ++o) acc[o] = bias[o];
#pragma unroll
    for (int k = 0; k < 9; ++k) {
        float v = hv[k];
        const float* wp = wTa + k * 32;
#pragma unroll
        for (int o = 0; o < 32; ++o) acc[o] = fmaf(v, wp[o], acc[o]);
    }
#pragma unroll
    for (int o = 0; o < 32; ++o) h[(size_t)o * NP + p] = fmaxf(acc[o], 0.f);
}

// ---------------- K7: 3x3 conv 32->64, pad 1, relu (the big one) ------------
__global__ __launch_bounds__(256) void k_c9b(const float* __restrict__ h,
                                             const float* __restrict__ wTb,
                                             const float* __restrict__ bias,
                                             float* __restrict__ out)
{
    int p = blockIdx.x * 256 + threadIdx.x;
    if (p >= NP) return;
    int y = p / 511, x = p - y * 511;
    bool ym = y > 0, yp = y < 510, xm = x > 0, xp = x < 510;

    float acc[64];
#pragma unroll
    for (int o = 0; o < 64; ++o) acc[o] = bias[o];

    for (int c = 0; c < 32; ++c) {
        const float* hc = h + (size_t)c * NP + p;
        float hv[9];
        hv[0] = (ym && xm) ? hc[-512] : 0.f;
        hv[1] = ym ? hc[-511] : 0.f;
        hv[2] = (ym && xp) ? hc[-510] : 0.f;
        hv[3] = xm ? hc[-1] : 0.f;
        hv[4] = hc[0];
        hv[5] = xp ? hc[1] : 0.f;
        hv[6] = (yp && xm) ? hc[510] : 0.f;
        hv[7] = yp ? hc[511] : 0.f;
        hv[8] = (yp && xp) ? hc[512] : 0.f;
#pragma unroll
        for (int k = 0; k < 9; ++k) {
            float v = hv[k];
            const float* wp = wTb + (c * 9 + k) * 64;
#pragma unroll
            for (int o = 0; o < 64; ++o) acc[o] = fmaf(v, wp[o], acc[o]);
        }
    }
#pragma unroll
    for (int o = 0; o < 64; ++o) out[(size_t)o * NP + p] = fmaxf(acc[o], 0.f);
}

// ---------------------------------------------------------------------------
extern "C" void kernel_launch(void* const* d_in, const int* in_sizes, int n_in,
                              void* d_out, int out_size, void* d_ws, size_t ws_size,
                              hipStream_t stream)
{
    (void)in_sizes; (void)n_in; (void)out_size; (void)ws_size;

    const float* x     = (const float*)d_in[0];
    const float* w_x1  = (const float*)d_in[1];
    const float* b_x1  = (const float*)d_in[2];
    const float* w_x2  = (const float*)d_in[3];
    const float* b_x2  = (const float*)d_in[4];
    const float* w_x3  = (const float*)d_in[5];
    const float* b_x3  = (const float*)d_in[6];
    const float* w_hi  = (const float*)d_in[7];
    const float* b_hi  = (const float*)d_in[8];
    // d_in[9] w_lo, d_in[10] b_lo, d_in[13] ca2_w1, d_in[14] ca2_w2: dead (alpha=1)
    const float* ca1w1 = (const float*)d_in[11];
    const float* ca1w2 = (const float*)d_in[12];
    const float* w_cat = (const float*)d_in[15];
    const float* b_cat = (const float*)d_in[16];
    const float* w_c9a = (const float*)d_in[17];
    const float* b_c9a = (const float*)d_in[18];
    const float* w_c9b = (const float*)d_in[19];
    const float* b_c9b = (const float*)d_in[20];

    float* ws    = (float*)d_ws;
    float* tmp12 = ws + 0;         // 261121 -> 261184
    float* hf    = ws + 261184;    // 266256 -> 266304
    float* hfb   = ws + 527488;    // 266256 -> 266304
    float* f12   = ws + 793792;    // 261121 -> 261184
    float* psum  = ws + 1054976;   // 256
    float* pmax  = ws + 1055232;   // 256
    float* scale = ws + 1055488;   // 1 -> 64
    float* wTa   = ws + 1055552;   // 288 -> 320
    float* wTb   = ws + 1055872;   // 18432
    float* hbuf  = ws + 1074304;   // 32*261121

    float* out = (float*)d_out;

    // gaussian_kernel5(0.5) computed on host in double, matching numpy
    double kk[5], ssum = 0.0;
    for (int i = 0; i < 5; ++i) { double r = i - 2.0; kk[i] = exp(-r * r / 0.5); ssum += kk[i]; }
    float g0 = (float)(kk[0] / ssum), g1 = (float)(kk[1] / ssum), g2 = (float)(kk[2] / ssum);

    k_prep<<<72, 256, 0, stream>>>(w_c9a, w_c9b, wTa, wTb);
    k_conv123<<<1021, 256, 0, stream>>>(x, w_x1, b_x1, w_x2, b_x2, w_x3, b_x3, tmp12);
    k_dwt_hi<<<261, 256, 0, stream>>>(tmp12, w_hi, b_hi, hf);
    k_blur<<<1041, 256, 0, stream>>>(hf, hfb, g0, g1, g2);
    k_red1<<<256, 256, 0, stream>>>(hfb, psum, pmax);
    k_red2<<<1, 256, 0, stream>>>(psum, pmax, ca1w1, ca1w2, scale);
    k_cat<<<1021, 256, 0, stream>>>(hfb, tmp12, w_cat, b_cat, scale, f12);
    k_c9a<<<1021, 256, 0, stream>>>(f12, wTa, b_c9a, hbuf);
    k_c9b<<<1021, 256, 0, stream>>>(hbuf, wTb, b_c9b, out);
}

// Round 2
// 123.365 us; speedup vs baseline: 2.0227x; 2.0227x over previous
//
#include <hip/hip_runtime.h>
#include <math.h>

#define NP 261121   // 511*511
#define WPX 520     // padded h2 row stride in pixels (rows 0..513, interior 1..511)

typedef __attribute__((ext_vector_type(8))) short short8;
typedef __attribute__((ext_vector_type(4))) float f32x4;

static __device__ __forceinline__ unsigned short f2bf(float f) {
    unsigned int u = __builtin_bit_cast(unsigned int, f);
    u += 0x7FFFu + ((u >> 16) & 1u);   // round-to-nearest-even
    return (unsigned short)(u >> 16);
}

// ---------------- K0: weight prep ------------------------------------------
// wTa[k*32+o] = w_c9a[o*9+k]          (fp32, for k_c9a)
// wb2[k*2048 + o*32 + c] = bf16(w_c9b[o*288 + c*9 + k])   (bf16, for MFMA c9b)
__global__ __launch_bounds__(256) void k_prep(const float* __restrict__ w_c9a,
                                              const float* __restrict__ w_c9b,
                                              float* __restrict__ wTa,
                                              unsigned short* __restrict__ wb2)
{
    int t = blockIdx.x * 256 + threadIdx.x;
    if (t < 288) {
        int o = t & 31, k = t >> 5;
        wTa[t] = w_c9a[o * 9 + k];
    }
    if (t < 18432) {
        int o = t / 288, ck = t - o * 288;
        int c = ck / 9, k = ck - c * 9;
        wb2[k * 2048 + o * 32 + c] = f2bf(w_c9b[t]);
    }
}

// ---------------- K0b: zero the pad ring of h2 ------------------------------
__global__ __launch_bounds__(256) void k_zero(unsigned short* __restrict__ h2)
{
    int t = blockIdx.x * 256 + threadIdx.x;
    const int ROWN = WPX * 32;            // 16640 ushorts per row
    if (t < 2 * ROWN) {                   // rows 0 and 512 full
        int r = t / ROWN;
        h2[(r ? 512 : 0) * ROWN + (t % ROWN)] = 0;
    }
    int u = t - 2 * ROWN;
    if (u >= 0 && u < 511 * 96) {         // cols 0, 512, 513 for rows 1..511
        int row = u / 96 + 1, cc = u - (u / 96) * 96;
        int col = (cc < 32) ? 0 : (cc < 64 ? 512 : 513);
        h2[(row * WPX + col) * 32 + (cc & 31)] = 0;
    }
}

// ---------------- K1: fused 1x1 convs 204->16->8->1 (relu each) -------------
__global__ __launch_bounds__(256) void k_conv123(const float* __restrict__ x,
                                                 const float* __restrict__ w1,
                                                 const float* __restrict__ b1,
                                                 const float* __restrict__ w2,
                                                 const float* __restrict__ b2,
                                                 const float* __restrict__ w3,
                                                 const float* __restrict__ b3,
                                                 float* __restrict__ tmp12)
{
    __shared__ float s_w1[204 * 16];
    __shared__ float s_misc[192];
    int t = threadIdx.x;
    for (int i = t; i < 204 * 16; i += 256)
        s_w1[i] = w1[(i & 15) * 204 + (i >> 4)];
    if (t < 128) s_misc[t] = w2[t];
    else if (t < 136) s_misc[t] = w3[t - 128];
    else if (t < 152) s_misc[t] = b1[t - 136];
    else if (t < 160) s_misc[t] = b2[t - 152];
    else if (t == 160) s_misc[160] = b3[0];
    __syncthreads();

    int p = blockIdx.x * 256 + t;
    if (p >= NP) return;

    float acc[16];
#pragma unroll
    for (int o = 0; o < 16; ++o) acc[o] = 0.f;

    const float* xp = x + p;
#pragma unroll 4
    for (int c = 0; c < 204; ++c) {
        float xv = xp[(size_t)c * NP];
        const float4* wv = reinterpret_cast<const float4*>(s_w1 + c * 16);
        float wl[16];
        *reinterpret_cast<float4*>(&wl[0])  = wv[0];
        *reinterpret_cast<float4*>(&wl[4])  = wv[1];
        *reinterpret_cast<float4*>(&wl[8])  = wv[2];
        *reinterpret_cast<float4*>(&wl[12]) = wv[3];
#pragma unroll
        for (int o = 0; o < 16; ++o) acc[o] = fmaf(xv, wl[o], acc[o]);
    }

    float f1[16];
#pragma unroll
    for (int o = 0; o < 16; ++o) f1[o] = fmaxf(acc[o] + s_misc[136 + o], 0.f);

    float tmp = s_misc[160];
#pragma unroll
    for (int j = 0; j < 8; ++j) {
        float s = s_misc[152 + j];
#pragma unroll
        for (int o = 0; o < 16; ++o) s = fmaf(f1[o], s_misc[j * 16 + o], s);
        tmp = fmaf(fmaxf(s, 0.f), s_misc[128 + j], tmp);
    }
    tmp12[p] = fmaxf(tmp, 0.f);
}

// ------------- K2: Haar DWT (zero-pad) + 1x1 conv(pad=1) + pixel_shuffle ----
__global__ __launch_bounds__(256) void k_dwt_hi(const float* __restrict__ tmp12,
                                                const float* __restrict__ w_hi,
                                                const float* __restrict__ b_hi,
                                                float* __restrict__ hf)
{
    const float INV = 0.70710678118654752440f;
    int idx = blockIdx.x * 256 + threadIdx.x;
    if (idx >= 258 * 258) return;
    int h = idx / 258, w = idx - h * 258;

    float wh[12], bh[4];
#pragma unroll
    for (int i = 0; i < 12; ++i) wh[i] = w_hi[i];
#pragma unroll
    for (int o = 0; o < 4; ++o) bh[o] = b_hi[o];

    float v[4];
    if (h == 0 || h == 257 || w == 0 || w == 257) {
#pragma unroll
        for (int o = 0; o < 4; ++o) v[o] = fmaxf(bh[o], 0.f);
    } else {
        int hh = h - 1, ww = w - 1;
        int r0 = 2 * hh, r1 = 2 * hh + 1, c0 = 2 * ww, c1 = 2 * ww + 1;
        float a = tmp12[r0 * 511 + c0];
        float b = (c1 < 511) ? tmp12[r0 * 511 + c1] : 0.f;
        float c = (r1 < 511) ? tmp12[r1 * 511 + c0] : 0.f;
        float d = (r1 < 511 && c1 < 511) ? tmp12[r1 * 511 + c1] : 0.f;
        float lo0 = (a + b) * INV, hi0 = (a - b) * INV;
        float lo1 = (c + d) * INV, hi1 = (c - d) * INV;
        float cH = (lo0 - lo1) * INV;
        float cV = (hi0 + hi1) * INV;
        float cD = (hi0 - hi1) * INV;
#pragma unroll
        for (int o = 0; o < 4; ++o)
            v[o] = fmaxf(wh[o * 3 + 0] * cH + wh[o * 3 + 1] * cV + wh[o * 3 + 2] * cD + bh[o], 0.f);
    }
    int orow = (2 * h) * 516 + 2 * w;
    hf[orow]       = v[0];
    hf[orow + 1]   = v[1];
    hf[orow + 516] = v[2];
    hf[orow + 517] = v[3];
}

// ---------------- K3: 5x5 separable gaussian blur, reflect pad --------------
__global__ __launch_bounds__(256) void k_blur(const float* __restrict__ hf,
                                              float* __restrict__ hfb,
                                              float g0, float g1, float g2)
{
    int idx = blockIdx.x * 256 + threadIdx.x;
    if (idx >= 516 * 516) return;
    int y = idx / 516, x = idx - y * 516;
    float g[5] = {g0, g1, g2, g1, g0};
    int ry[5], rx[5];
#pragma unroll
    for (int i = 0; i < 5; ++i) {
        int yy = y + i - 2; yy = yy < 0 ? -yy : (yy > 515 ? 1030 - yy : yy);
        int xx = x + i - 2; xx = xx < 0 ? -xx : (xx > 515 ? 1030 - xx : xx);
        ry[i] = yy * 516; rx[i] = xx;
    }
    float s = 0.f;
#pragma unroll
    for (int i = 0; i < 5; ++i) {
        float rs = 0.f;
#pragma unroll
        for (int j = 0; j < 5; ++j) rs = fmaf(g[j], hf[ry[i] + rx[j]], rs);
        s = fmaf(g[i], rs, s);
    }
    hfb[idx] = s;
}

// ---------------- K4: global mean/max reduction -> sigmoid gate -------------
__global__ __launch_bounds__(256) void k_red1(const float* __restrict__ hfb,
                                              float* __restrict__ psum,
                                              float* __restrict__ pmax)
{
    __shared__ float ss[256], sm[256];
    int t = threadIdx.x;
    int gid = blockIdx.x * 256 + t;
    float s = 0.f, m = -3.4e38f;
    for (int i = gid; i < 516 * 516; i += 65536) { float v = hfb[i]; s += v; m = fmaxf(m, v); }
    ss[t] = s; sm[t] = m;
    __syncthreads();
    for (int off = 128; off > 0; off >>= 1) {
        if (t < off) { ss[t] += ss[t + off]; sm[t] = fmaxf(sm[t], sm[t + off]); }
        __syncthreads();
    }
    if (t == 0) { psum[blockIdx.x] = ss[0]; pmax[blockIdx.x] = sm[0]; }
}

__global__ __launch_bounds__(256) void k_red2(const float* __restrict__ psum,
                                              const float* __restrict__ pmax,
                                              const float* __restrict__ caw1,
                                              const float* __restrict__ caw2,
                                              float* __restrict__ scale)
{
    __shared__ float ss[256], sm[256];
    int t = threadIdx.x;
    ss[t] = psum[t]; sm[t] = pmax[t];
    __syncthreads();
    for (int off = 128; off > 0; off >>= 1) {
        if (t < off) { ss[t] += ss[t + off]; sm[t] = fmaxf(sm[t], sm[t + off]); }
        __syncthreads();
    }
    if (t == 0) {
        float avg = ss[0] / 266256.f;
        float mx = sm[0];
        float a = caw1[0], b = caw2[0];
        float z = b * fmaxf(a * avg, 0.f) + b * fmaxf(a * mx, 0.f);
        scale[0] = 1.f / (1.f + expf(-z));
    }
}

// ---------------- K5: 6x6 valid conv (scale folded) + bias + relu + residual
__global__ __launch_bounds__(256) void k_cat(const float* __restrict__ hfb,
                                             const float* __restrict__ tmp12,
                                             const float* __restrict__ w_cat,
                                             const float* __restrict__ b_cat,
                                             const float* __restrict__ scale,
                                             float* __restrict__ f12)
{
    int p = blockIdx.x * 256 + threadIdx.x;
    if (p >= NP) return;
    int y = p / 511, x = p - y * 511;
    float sc = scale[0];
    float s = 0.f;
#pragma unroll
    for (int ky = 0; ky < 6; ++ky) {
        const float* row = hfb + (y + ky) * 516 + x;
#pragma unroll
        for (int kx = 0; kx < 6; ++kx) s = fmaf(row[kx], w_cat[ky * 6 + kx], s);
    }
    f12[p] = tmp12[p] + fmaxf(sc * s + b_cat[0], 0.f);
}

// ---------------- K6: 3x3 conv 1->32, pad 1, relu -> bf16 pixel-major h2 ----
__global__ __launch_bounds__(256) void k_c9a(const float* __restrict__ f12,
                                             const float* __restrict__ wTa,
                                             const float* __restrict__ bias,
                                             unsigned short* __restrict__ h2)
{
    int p = blockIdx.x * 256 + threadIdx.x;
    if (p >= NP) return;
    int y = p / 511, x = p - y * 511;
    float hv[9];
#pragma unroll
    for (int ky = 0; ky < 3; ++ky)
#pragma unroll
        for (int kx = 0; kx < 3; ++kx) {
            int yy = y + ky - 1, xx = x + kx - 1;
            hv[ky * 3 + kx] = (yy >= 0 && yy < 511 && xx >= 0 && xx < 511) ? f12[yy * 511 + xx] : 0.f;
        }
    float acc[32];
#pragma unroll
    for (int o = 0; o < 32; ++o) acc[o] = bias[o];
#pragma unroll
    for (int k = 0; k < 9; ++k) {
        float v = hv[k];
        const float* wp = wTa + k * 32;
#pragma unroll
        for (int o = 0; o < 32; ++o) acc[o] = fmaf(v, wp[o], acc[o]);
    }
    unsigned short o16[32];
#pragma unroll
    for (int o = 0; o < 32; ++o) o16[o] = f2bf(fmaxf(acc[o], 0.f));
    unsigned short* dst = h2 + ((size_t)(y + 1) * WPX + (x + 1)) * 32;
#pragma unroll
    for (int i = 0; i < 4; ++i)
        reinterpret_cast<short8*>(dst)[i] = reinterpret_cast<const short8*>(o16)[i];
}

// ---------------- K7: 3x3 conv 32->64 via MFMA implicit GEMM ----------------
// wave = 64 px strip x 64 out channels; per tap: A(64x32 weights) * B(32ch x 64px)
__global__ __launch_bounds__(256, 2) void k_c9b(const unsigned short* __restrict__ h2,
                                                const unsigned short* __restrict__ wb2,
                                                const float* __restrict__ bias,
                                                float* __restrict__ out)
{
    int wave = threadIdx.x >> 6, lane = threadIdx.x & 63;
    int y  = blockIdx.x >> 1;                 // 0..510
    int xh = blockIdx.x & 1;
    int xb = xh * 256 + wave * 64;            // wave's 64-px strip start
    int lpx = lane & 15, kg = lane >> 4;      // px-in-frag, k-group (8 channels)

    f32x4 acc[4][4];
#pragma unroll
    for (int m = 0; m < 4; ++m)
#pragma unroll
        for (int n = 0; n < 4; ++n) acc[m][n] = (f32x4){0.f, 0.f, 0.f, 0.f};

    // base index (ushorts) of this lane's B-frag at tap (0,0), n=0
    const int base = (((y + 1) * WPX) + (xb + 1) + lpx) * 32 + kg * 8;

#pragma unroll
    for (int kt = 0; kt < 9; ++kt) {
        const int dy = kt / 3 - 1, dx = kt % 3 - 1;
        const int toff = (dy * WPX + dx) * 32;

        short8 a[4], b[4];
        const short8* wp = reinterpret_cast<const short8*>(wb2 + kt * 2048 + kg * 8);
#pragma unroll
        for (int m = 0; m < 4; ++m) a[m] = wp[(m * 16 + lpx) * 4];
#pragma unroll
        for (int n = 0; n < 4; ++n)
            b[n] = *reinterpret_cast<const short8*>(h2 + base + toff + n * 512);
#pragma unroll
        for (int m = 0; m < 4; ++m)
#pragma unroll
            for (int n = 0; n < 4; ++n)
                acc[m][n] = __builtin_amdgcn_mfma_f32_16x16x32_bf16(a[m], b[n], acc[m][n], 0, 0, 0);
    }

    const int ybase = y * 511;
#pragma unroll
    for (int m = 0; m < 4; ++m) {
#pragma unroll
        for (int r = 0; r < 4; ++r) {
            int o = m * 16 + kg * 4 + r;
            float bo = bias[o];
#pragma unroll
            for (int n = 0; n < 4; ++n) {
                int px = xb + n * 16 + lpx;
                if (px < 511)
                    out[(size_t)o * NP + ybase + px] = fmaxf(acc[m][n][r] + bo, 0.f);
            }
        }
    }
}

// ---------------------------------------------------------------------------
extern "C" void kernel_launch(void* const* d_in, const int* in_sizes, int n_in,
                              void* d_out, int out_size, void* d_ws, size_t ws_size,
                              hipStream_t stream)
{
    (void)in_sizes; (void)n_in; (void)out_size; (void)ws_size;

    const float* x     = (const float*)d_in[0];
    const float* w_x1  = (const float*)d_in[1];
    const float* b_x1  = (const float*)d_in[2];
    const float* w_x2  = (const float*)d_in[3];
    const float* b_x2  = (const float*)d_in[4];
    const float* w_x3  = (const float*)d_in[5];
    const float* b_x3  = (const float*)d_in[6];
    const float* w_hi  = (const float*)d_in[7];
    const float* b_hi  = (const float*)d_in[8];
    const float* ca1w1 = (const float*)d_in[11];
    const float* ca1w2 = (const float*)d_in[12];
    const float* w_cat = (const float*)d_in[15];
    const float* b_cat = (const float*)d_in[16];
    const float* w_c9a = (const float*)d_in[17];
    const float* b_c9a = (const float*)d_in[18];
    const float* w_c9b = (const float*)d_in[19];
    const float* b_c9b = (const float*)d_in[20];

    float* ws    = (float*)d_ws;
    float* tmp12 = ws + 0;                       // 261184
    float* hf    = ws + 261184;                  // 266304
    float* hfb   = ws + 527488;                  // 266304
    float* f12   = ws + 793792;                  // 261184
    float* psum  = ws + 1054976;                 // 256
    float* pmax  = ws + 1055232;                 // 256
    float* scale = ws + 1055488;                 // 64
    float* wTa   = ws + 1055552;                 // 320
    unsigned short* wb2 = (unsigned short*)(ws + 1055872);   // 18432 ushorts (9216 f)
    unsigned short* h2  = (unsigned short*)(ws + 1065088);   // 514*520*32 ushorts

    float* out = (float*)d_out;

    double kk[5], ssum = 0.0;
    for (int i = 0; i < 5; ++i) { double r = i - 2.0; kk[i] = exp(-r * r / 0.5); ssum += kk[i]; }
    float g0 = (float)(kk[0] / ssum), g1 = (float)(kk[1] / ssum), g2 = (float)(kk[2] / ssum);

    k_prep<<<72, 256, 0, stream>>>(w_c9a, w_c9b, wTa, wb2);
    k_zero<<<322, 256, 0, stream>>>(h2);
    k_conv123<<<1021, 256, 0, stream>>>(x, w_x1, b_x1, w_x2, b_x2, w_x3, b_x3, tmp12);
    k_dwt_hi<<<261, 256, 0, stream>>>(tmp12, w_hi, b_hi, hf);
    k_blur<<<1041, 256, 0, stream>>>(hf, hfb, g0, g1, g2);
    k_red1<<<256, 256, 0, stream>>>(hfb, psum, pmax);
    k_red2<<<1, 256, 0, stream>>>(psum, pmax, ca1w1, ca1w2, scale);
    k_cat<<<1021, 256, 0, stream>>>(hfb, tmp12, w_cat, b_cat, scale, f12);
    k_c9a<<<1021, 256, 0, stream>>>(f12, wTa, b_c9a, h2);
    k_c9b<<<1022, 256, 0, stream>>>(h2, wb2, b_c9b, out);
}